// Round 5
// baseline (326.572 us; speedup 1.0000x reference)
//
#include <hip/hip_runtime.h>
#include <math.h>

// ---------- helpers ----------
__device__ __forceinline__ ushort f2bf(float f) {
    unsigned int u = __float_as_uint(f);
    u += 0x7FFFu + ((u >> 16) & 1u);   // round-to-nearest-even
    return (ushort)(u >> 16);
}

typedef __attribute__((address_space(1))) const unsigned int guint;
typedef __attribute__((address_space(3))) unsigned int luint;
__device__ __forceinline__ void gload_lds16(const void* g, void* l) {
    __builtin_amdgcn_global_load_lds((guint*)g, (luint*)l, 16, 0, 0);
}

using bfrag = __attribute__((ext_vector_type(8))) short;   // 8 bf16 = 4 VGPR
using f4    = __attribute__((ext_vector_type(4))) float;

__device__ __forceinline__ void bf8_to_f(uint4 v, float* o) {
    unsigned int u[4] = {v.x, v.y, v.z, v.w};
    #pragma unroll
    for (int i = 0; i < 4; ++i) {
        o[2 * i]     = __uint_as_float(u[i] << 16);
        o[2 * i + 1] = __uint_as_float(u[i] & 0xFFFF0000u);
    }
}

// ---------- weight cvt + reorder: w[m][c][r] fp32 -> wq[m][r*256+c] bf16 ----------
struct CvtArgs {
    const float* src[7];
    ushort*      dst[7];
    int          m[7];      // rows (256 or 27)
};
__global__ __launch_bounds__(256) void cvt_kernel(CvtArgs a) {
    int t = blockIdx.y;
    int idx = blockIdx.x * 256 + threadIdx.x;    // m*288 + r*32 + c8
    int M = a.m[t];
    if (idx >= M * 288) return;
    int m = idx / 288, rem = idx - m * 288;
    int r = rem >> 5, c8 = rem & 31;
    const float* s = a.src[t] + ((size_t)(m * 256 + c8 * 8)) * 9 + r;
    ushort vals[8];
    #pragma unroll
    for (int j = 0; j < 8; ++j) vals[j] = f2bf(s[j * 9]);
    *(uint4*)&a.dst[t][(size_t)m * 2304 + r * 256 + c8 * 8] = *(uint4*)vals;
}

// ---------- fused prefill: bias into all 4 out levels + zero offbuf/zeropage ----------
struct FillArgs {
    float* outp[4];
    const float* bias[4];
    int HW[4];
    float* zbase;
    int z4;      // float4 count to zero
};
__global__ __launch_bounds__(256) void fill_kernel(FillArgs a) {
    int y = blockIdx.y;
    int i = blockIdx.x * 256 + threadIdx.x;
    if (y < 4) {
        int HW = a.HW[y];
        int total4 = (2 * 256 * HW) >> 2;     // HW % 4 == 0 for all levels
        if (i < total4) {
            int e = i << 2;
            int m = (e / HW) & 255;
            float v = a.bias[y][m];
            *(float4*)&a.outp[y][e] = float4{v, v, v, v};
        }
    } else {
        if (i < a.z4) ((float4*)a.zbase)[i] = float4{0.f, 0.f, 0.f, 0.f};
    }
}

// ---------- xs = NHWC bf16 of (x + up2(prev)); x,prev NCHW fp32 ----------
// grid: (ceil(HW/64), 8, B), block 256
__global__ __launch_bounds__(256) void xs_nhwc(
    const float* __restrict__ x, const float* __restrict__ prev,
    ushort* __restrict__ xs, int H, int W)
{
    __shared__ ushort tile[32][72];
    const int HW = H * W, W2 = W >> 1;
    int b = blockIdx.z, c0 = blockIdx.y * 32, hw0 = blockIdx.x * 64;
    const float* xb = x + ((size_t)b * 256 + c0) * HW;
    const float* pb = prev ? prev + ((size_t)b * 256 + c0) * (HW >> 2) : nullptr;

    int hwl = threadIdx.x & 63, cl0 = threadIdx.x >> 6;
    int hw = hw0 + hwl;
    bool ok = hw < HW;
    int hwc = ok ? hw : HW - 1;
    int h = hwc / W, w = hwc - h * W;
    int pidx = (h >> 1) * W2 + (w >> 1);
    #pragma unroll
    for (int p = 0; p < 8; ++p) {
        int cl = p * 4 + cl0;
        float v = 0.f;
        if (ok) {
            v = xb[(size_t)cl * HW + hw];
            if (pb) v += pb[(size_t)cl * (HW >> 2) + pidx];
        }
        tile[cl][hwl] = f2bf(v);
    }
    __syncthreads();
    int hwl2 = threadIdx.x >> 2, cc = (threadIdx.x & 3) * 8;
    int hw2 = hw0 + hwl2;
    if (hw2 < HW) {
        ushort vals[8];
        #pragma unroll
        for (int j = 0; j < 8; ++j) vals[j] = tile[cc + j][hwl2];
        *(uint4*)&xs[((size_t)b * HW + hw2) * 256 + c0 + cc] = *(uint4*)vals;
    }
}

// ---------- offset conv: bf16 MFMA, M=27 (pad 32), split-K, dbuf ----------
// grid: (ceil(N/64), 72/ktiles, B)
__global__ __launch_bounds__(256) void off_mfma(
    const ushort* __restrict__ A, const ushort* __restrict__ xs,
    const ushort* __restrict__ zeros, float* __restrict__ offbuf,
    int N, int H, int W, int ktiles)
{
    __shared__ __align__(16) ushort As[2][32 * 32];
    __shared__ __align__(16) ushort Bs[2][64 * 32];
    const int b  = blockIdx.z;
    const int n0 = blockIdx.x * 64;
    const int kt0 = blockIdx.y * ktiles * 32;
    const int tid = threadIdx.x, lane = tid & 63, wv = tid >> 6;
    const ushort* xb = xs + (size_t)b * N * 256;

    int n = n0 + (tid >> 2); if (n >= N) n = N - 1;
    int h = n / W, w = n - h * W;
    int kcc = (tid & 3) * 8;

    auto stage = [&](int kt, int bi) {
        int r = kt >> 8, c0k = kt & 255;
        int ry = r / 3 - 1, rx = r - (r / 3) * 3 - 1;
        if (tid < 128) {
            int row = tid >> 2; if (row > 26) row = 26;
            gload_lds16(A + (size_t)row * 2304 + kt + kcc,
                        (char*)As[bi] + (size_t)(tid & ~63) * 16);
        }
        int ih = h + ry, iw = w + rx;
        const ushort* src = (ih >= 0 && ih < H && iw >= 0 && iw < W)
            ? xb + (((size_t)(ih * W + iw)) << 8) + c0k + kcc
            : zeros;
        gload_lds16(src, (char*)Bs[bi] + (size_t)(tid & ~63) * 16);
    };

    f4 acc[2] = {};
    stage(kt0, 0);
    for (int kk = 0; kk < ktiles; ++kk) {
        __syncthreads();
        if (kk + 1 < ktiles) stage(kt0 + (kk + 1) * 32, (kk + 1) & 1);
        const ushort* as = As[kk & 1];
        const ushort* bs = Bs[kk & 1];
        bfrag bf = *(const bfrag*)&bs[(wv * 16 + (lane & 15)) * 32 + (lane >> 4) * 8];
        bfrag a0 = *(const bfrag*)&as[(lane & 15) * 32 + (lane >> 4) * 8];
        bfrag a1 = *(const bfrag*)&as[(16 + (lane & 15)) * 32 + (lane >> 4) * 8];
        acc[0] = __builtin_amdgcn_mfma_f32_16x16x32_bf16(a0, bf, acc[0], 0, 0, 0);
        acc[1] = __builtin_amdgcn_mfma_f32_16x16x32_bf16(a1, bf, acc[1], 0, 0, 0);
    }

    int nn = n0 + wv * 16 + (lane & 15);
    if (nn < N) {
        #pragma unroll
        for (int mb = 0; mb < 2; ++mb)
            #pragma unroll
            for (int t = 0; t < 4; ++t) {
                int m = mb * 16 + (lane >> 4) * 4 + t;
                if (m < 27)
                    atomicAdd(&offbuf[((size_t)b * 27 + m) * N + nn], acc[mb][t]);
            }
    }
}

// ---------- deformable sampling (NHWC) -> cols[b][hw][r*256+c] bf16 ----------
// grid: (ceil(HW/32), 1, B), block 256 = 32 hw x 8 c-blocks; geometry cached in LDS
__global__ __launch_bounds__(256) void sampling_kernel(
    const ushort* __restrict__ xs, const float* __restrict__ off,
    const float* __restrict__ ob, ushort* __restrict__ cols,
    int H, int W)
{
    __shared__ float4 gw[32][9];
    __shared__ int4   go[32][9];
    const int HW = H * W;
    const int b = blockIdx.z;
    const int hw0 = blockIdx.x * 32;
    const int tid = threadIdx.x;
    const float* offb = off + (size_t)b * 27 * HW;
    const ushort* xb = xs + (size_t)b * HW * 256;

    for (int it = tid; it < 32 * 9; it += 256) {
        int hwl = it / 9, k = it - hwl * 9;
        int hw = hw0 + hwl; if (hw >= HW) hw = HW - 1;
        int h = hw / W, w = hw - h * W;
        float dy = offb[(size_t)(2 * k) * HW + hw] + ob[2 * k];
        float dx = offb[(size_t)(2 * k + 1) * HW + hw] + ob[2 * k + 1];
        float mv = offb[(size_t)(18 + k) * HW + hw] + ob[18 + k];
        float mk = 1.0f / (1.0f + __expf(-mv));
        float py = (float)h - 1.0f + (float)(k / 3) + dy;
        float px = (float)w - 1.0f + (float)(k % 3) + dx;
        float y0f = floorf(py), x0f = floorf(px);
        float wy = py - y0f, wx = px - x0f;
        int y0 = (int)y0f, x0i = (int)x0f;
        int y1 = y0 + 1, x1 = x0i + 1;
        bool vy0 = (y0 >= 0) & (y0 < H), vy1 = (y1 >= 0) & (y1 < H);
        bool vx0 = (x0i >= 0) & (x0i < W), vx1 = (x1 >= 0) & (x1 < W);
        float w00 = (1.f - wy) * (1.f - wx) * ((vy0 & vx0) ? mk : 0.f);
        float w01 = (1.f - wy) * wx        * ((vy0 & vx1) ? mk : 0.f);
        float w10 = wy * (1.f - wx)        * ((vy1 & vx0) ? mk : 0.f);
        float w11 = wy * wx                * ((vy1 & vx1) ? mk : 0.f);
        int cy0 = min(max(y0, 0), H - 1), cy1 = min(max(y1, 0), H - 1);
        int cx0 = min(max(x0i, 0), W - 1), cx1 = min(max(x1, 0), W - 1);
        gw[hwl][k] = float4{w00, w01, w10, w11};
        go[hwl][k] = int4{(cy0 * W + cx0) << 8, (cy0 * W + cx1) << 8,
                          (cy1 * W + cx0) << 8, (cy1 * W + cx1) << 8};
    }
    __syncthreads();

    int hwl = tid >> 3, cb = (tid & 7) * 32;
    int hw = hw0 + hwl;
    if (hw >= HW) return;
    ushort* colp = cols + ((size_t)b * HW + hw) * 2304 + cb;

    #pragma unroll
    for (int k = 0; k < 9; ++k) {
        float4 wv = gw[hwl][k];
        int4   ov = go[hwl][k];
        const ushort* p00 = xb + ov.x + cb;
        const ushort* p01 = xb + ov.y + cb;
        const ushort* p10 = xb + ov.z + cb;
        const ushort* p11 = xb + ov.w + cb;
        #pragma unroll
        for (int j = 0; j < 4; ++j) {
            float f00[8], f01[8], f10[8], f11[8];
            bf8_to_f(*(const uint4*)(p00 + 8 * j), f00);
            bf8_to_f(*(const uint4*)(p01 + 8 * j), f01);
            bf8_to_f(*(const uint4*)(p10 + 8 * j), f10);
            bf8_to_f(*(const uint4*)(p11 + 8 * j), f11);
            unsigned int pk[4];
            #pragma unroll
            for (int t = 0; t < 4; ++t) {
                float lo = f00[2 * t] * wv.x + f01[2 * t] * wv.y +
                           f10[2 * t] * wv.z + f11[2 * t] * wv.w;
                float hi = f00[2 * t + 1] * wv.x + f01[2 * t + 1] * wv.y +
                           f10[2 * t + 1] * wv.z + f11[2 * t + 1] * wv.w;
                pk[t] = (unsigned int)f2bf(lo) | ((unsigned int)f2bf(hi) << 16);
            }
            *(uint4*)(colp + k * 256 + 8 * j) = make_uint4(pk[0], pk[1], pk[2], pk[3]);
        }
    }
}

// ---------- bf16 MFMA GEMM: A[256][K], B = cols[N][K] or NHWC implicit ----------
// grid: (ceil(N/128), 2*S, B); kchunk = 2304/S; dbuf single-barrier K-loop.
template<bool IMPLICIT, bool SPLITK>
__global__ __launch_bounds__(256) void mfma_gemm(
    const ushort* __restrict__ A, const float* __restrict__ bias,
    const ushort* __restrict__ Bt, const ushort* __restrict__ zeros,
    float* __restrict__ outp, int N, int H, int W, int kchunk)
{
    __shared__ __align__(16) ushort As[2][128 * 32];
    __shared__ __align__(16) ushort Bs[2][128 * 32];
    const int b  = blockIdx.z;
    const int m0 = (blockIdx.y & 1) * 128;
    const int kt0 = (blockIdx.y >> 1) * kchunk;
    const int n0 = blockIdx.x * 128;
    const int tid  = threadIdx.x;
    const int lane = tid & 63;
    const int wv   = tid >> 6;
    const int wm = wv >> 1, wn = wv & 1;
    const int kcc = (tid & 3) * 8;

    const ushort* Bb = IMPLICIT ? Bt + (size_t)b * N * 256
                                : Bt + (size_t)b * (size_t)N * 2304;

    int nn2[2], hh[2], ww[2];
    #pragma unroll
    for (int j = 0; j < 2; ++j) {
        int n = n0 + j * 64 + (tid >> 2); if (n >= N) n = N - 1;
        nn2[j] = n;
        hh[j] = n / W; ww[j] = n - hh[j] * W;
    }

    auto stage = [&](int kt, int bi) {
        #pragma unroll
        for (int j = 0; j < 2; ++j) {
            int row = j * 64 + (tid >> 2);
            gload_lds16(A + (size_t)(m0 + row) * 2304 + kt + kcc,
                        (char*)As[bi] + (size_t)(j * 256 + (tid & ~63)) * 16);
        }
        if (!IMPLICIT) {
            #pragma unroll
            for (int j = 0; j < 2; ++j) {
                gload_lds16(Bb + (size_t)nn2[j] * 2304 + kt + kcc,
                            (char*)Bs[bi] + (size_t)(j * 256 + (tid & ~63)) * 16);
            }
        } else {
            int r = kt >> 8, c0k = kt & 255;
            int ry = r / 3 - 1, rx = r - (r / 3) * 3 - 1;
            #pragma unroll
            for (int j = 0; j < 2; ++j) {
                int ih = hh[j] + ry, iw = ww[j] + rx;
                const ushort* src = (ih >= 0 && ih < H && iw >= 0 && iw < W)
                    ? Bb + (((size_t)(ih * W + iw)) << 8) + c0k + kcc
                    : zeros;
                gload_lds16(src, (char*)Bs[bi] + (size_t)(j * 256 + (tid & ~63)) * 16);
            }
        }
    };

    f4 acc[4][4] = {};
    const int nit = kchunk >> 5;
    stage(kt0, 0);
    for (int it = 0; it < nit; ++it) {
        __syncthreads();                       // drains buf[it&1] loads (overlapped prev MFMA)
        if (it + 1 < nit) stage(kt0 + (it + 1) * 32, (it + 1) & 1);
        const ushort* as = As[it & 1];
        const ushort* bs = Bs[it & 1];
        bfrag af[4], bf[4];
        #pragma unroll
        for (int i = 0; i < 4; ++i)
            af[i] = *(const bfrag*)&as[(wm * 64 + i * 16 + (lane & 15)) * 32 + (lane >> 4) * 8];
        #pragma unroll
        for (int j = 0; j < 4; ++j)
            bf[j] = *(const bfrag*)&bs[(wn * 64 + j * 16 + (lane & 15)) * 32 + (lane >> 4) * 8];
        #pragma unroll
        for (int i = 0; i < 4; ++i)
            #pragma unroll
            for (int j = 0; j < 4; ++j)
                acc[i][j] = __builtin_amdgcn_mfma_f32_16x16x32_bf16(af[i], bf[j], acc[i][j], 0, 0, 0);
    }

    const int mb = m0 + wm * 64, nb = n0 + wn * 64;
    #pragma unroll
    for (int i = 0; i < 4; ++i) {
        int mrow = mb + i * 16 + (lane >> 4) * 4;
        #pragma unroll
        for (int j = 0; j < 4; ++j) {
            int n = nb + j * 16 + (lane & 15);
            if (n < N) {
                #pragma unroll
                for (int t = 0; t < 4; ++t) {
                    int m = mrow + t;
                    if (SPLITK)
                        atomicAdd(&outp[((size_t)b * 256 + m) * N + n], acc[i][j][t]);
                    else
                        outp[((size_t)b * 256 + m) * N + n] = acc[i][j][t] + bias[m];
                }
            }
        }
    }
}

// ---------- host launch ----------
extern "C" void kernel_launch(void* const* d_in, const int* in_sizes, int n_in,
                              void* d_out, int out_size, void* d_ws, size_t ws_size,
                              hipStream_t stream)
{
    const float* x[4]   = {(const float*)d_in[0], (const float*)d_in[1],
                           (const float*)d_in[2], (const float*)d_in[3]};
    const float* wgt[4] = {(const float*)d_in[4], (const float*)d_in[6],
                           (const float*)d_in[8], (const float*)d_in[10]};
    const float* bia[4] = {(const float*)d_in[5], (const float*)d_in[7],
                           (const float*)d_in[9], (const float*)d_in[11]};
    const float* owt[4] = {nullptr, (const float*)d_in[12],
                           (const float*)d_in[14], (const float*)d_in[16]};
    const float* obv[4] = {nullptr, (const float*)d_in[13],
                           (const float*)d_in[15], (const float*)d_in[17]};

    const int B = 2;
    const int Hs[4] = {96, 48, 24, 12};
    const int HWs[4] = {96 * 96, 48 * 48, 24 * 24, 12 * 12};

    float* out = (float*)d_out;
    size_t outOff[4];
    outOff[0] = 0;
    outOff[1] = outOff[0] + (size_t)B * 256 * HWs[0];
    outOff[2] = outOff[1] + (size_t)B * 256 * HWs[1];
    outOff[3] = outOff[2] + (size_t)B * 256 * HWs[2];

    // ---- ws carve (256B aligned)
    char* ws = (char*)d_ws;
    size_t off = 0;
    auto carve = [&](size_t bytes) { void* p = ws + off; off = (off + bytes + 255) & ~(size_t)255; return p; };
    ushort* wbf[4];
    ushort* owbf[4] = {nullptr, nullptr, nullptr, nullptr};
    for (int i = 0; i < 4; ++i) wbf[i] = (ushort*)carve((size_t)256 * 2304 * 2);
    for (int i = 1; i < 4; ++i) owbf[i] = (ushort*)carve((size_t)27 * 2304 * 2);
    ushort* cols = (ushort*)carve((size_t)B * HWs[1] * 2304 * 2);   // max: level 1
    ushort* xsb[4];
    for (int i = 0; i < 4; ++i) xsb[i] = (ushort*)carve((size_t)B * 256 * HWs[i] * 2);
    int offElems = B * 27 * (HWs[1] + HWs[2] + HWs[3]);
    float* offbase = (float*)carve((size_t)offElems * 4 + 1024);
    ushort* zeros = (ushort*)(offbase + offElems);   // 1 KB zero page
    float* offbuf[4] = {nullptr,
                        offbase,
                        offbase + (size_t)B * 27 * HWs[1],
                        offbase + (size_t)B * 27 * (HWs[1] + HWs[2])};

    // ---- upfront: weight cvt+reorder
    {
        CvtArgs a;
        a.src[0] = wgt[0]; a.src[1] = wgt[1]; a.src[2] = wgt[2]; a.src[3] = wgt[3];
        a.src[4] = owt[1]; a.src[5] = owt[2]; a.src[6] = owt[3];
        a.dst[0] = wbf[0]; a.dst[1] = wbf[1]; a.dst[2] = wbf[2]; a.dst[3] = wbf[3];
        a.dst[4] = owbf[1]; a.dst[5] = owbf[2]; a.dst[6] = owbf[3];
        for (int i = 0; i < 4; ++i) a.m[i] = 256;
        for (int i = 4; i < 7; ++i) a.m[i] = 27;
        dim3 grd((256 * 288 + 255) / 256, 7);
        cvt_kernel<<<grd, 256, 0, stream>>>(a);
    }
    // ---- upfront: fused bias prefill (all levels) + offbuf/zeropage zero
    {
        FillArgs a;
        for (int i = 0; i < 4; ++i) { a.outp[i] = out + outOff[i]; a.bias[i] = bia[i]; a.HW[i] = HWs[i]; }
        a.zbase = offbase;
        a.z4 = (offElems * 4 + 1024) / 16;
        dim3 grd((2 * 256 * HWs[0] / 4 + 255) / 256, 5);
        fill_kernel<<<grd, 256, 0, stream>>>(a);
    }
    {
        dim3 grd((HWs[3] + 63) / 64, 8, B);
        xs_nhwc<<<grd, 256, 0, stream>>>(x[3], nullptr, xsb[3], Hs[3], Hs[3]);
    }

    const int ktiles[4] = {0, 9, 6, 3};    // off-conv split-K chunking
    const int ksplit[4] = {2, 3, 8, 18};   // main-gemm split-K (divides 72)

    for (int lvl = 3; lvl >= 1; --lvl) {
        int H = Hs[lvl], W = H, HW = HWs[lvl];

        // offset conv (bf16 MFMA split-K, NHWC implicit staging, dbuf)
        {
            dim3 grd((HW + 63) / 64, 72 / ktiles[lvl], B);
            off_mfma<<<grd, 256, 0, stream>>>(
                owbf[lvl], xsb[lvl], zeros, offbuf[lvl], HW, H, W, ktiles[lvl]);
        }
        // deformable sampling -> cols [b][hw][r*256+c]
        {
            dim3 grd((HW + 31) / 32, 1, B);
            sampling_kernel<<<grd, 256, 0, stream>>>(
                xsb[lvl], offbuf[lvl], obv[lvl], cols, H, W);
        }
        // main conv: split-K MFMA GEMM into bias-prefilled out
        {
            dim3 grd((HW + 127) / 128, 2 * ksplit[lvl], B);
            mfma_gemm<false, true><<<grd, 256, 0, stream>>>(
                wbf[lvl], bia[lvl], cols, zeros, out + outOff[lvl],
                HW, H, W, 2304 / ksplit[lvl]);
        }
        // xs for next-finer level
        {
            int Hn = Hs[lvl - 1];
            dim3 grd((HWs[lvl - 1] + 63) / 64, 8, B);
            xs_nhwc<<<grd, 256, 0, stream>>>(
                x[lvl - 1], out + outOff[lvl], xsb[lvl - 1], Hn, Hn);
        }
    }

    // level 0: implicit NHWC MFMA GEMM, split-K S=2 into bias-prefilled out
    {
        dim3 grd((HWs[0] + 127) / 128, 2 * ksplit[0], B);
        mfma_gemm<true, true><<<grd, 256, 0, stream>>>(
            wbf[0], bia[0], xsb[0], zeros, out + outOff[0],
            HWs[0], Hs[0], Hs[0], 2304 / ksplit[0]);
    }
}

// Round 6
// 294.004 us; speedup vs baseline: 1.1108x; 1.1108x over previous
//
#include <hip/hip_runtime.h>
#include <math.h>

// ---------- helpers ----------
__device__ __forceinline__ ushort f2bf(float f) {
    unsigned int u = __float_as_uint(f);
    u += 0x7FFFu + ((u >> 16) & 1u);   // round-to-nearest-even
    return (ushort)(u >> 16);
}

typedef __attribute__((address_space(1))) const unsigned int guint;
typedef __attribute__((address_space(3))) unsigned int luint;
__device__ __forceinline__ void gload_lds16(const void* g, void* l) {
    __builtin_amdgcn_global_load_lds((guint*)g, (luint*)l, 16, 0, 0);
}

using bfrag = __attribute__((ext_vector_type(8))) short;   // 8 bf16 = 4 VGPR
using f4    = __attribute__((ext_vector_type(4))) float;

__device__ __forceinline__ void bf8_to_f(uint4 v, float* o) {
    unsigned int u[4] = {v.x, v.y, v.z, v.w};
    #pragma unroll
    for (int i = 0; i < 4; ++i) {
        o[2 * i]     = __uint_as_float(u[i] << 16);
        o[2 * i + 1] = __uint_as_float(u[i] & 0xFFFF0000u);
    }
}

// ---------- weight cvt + reorder: w[m][c][r] fp32 -> wq[m][r*256+c] bf16 ----------
struct CvtArgs {
    const float* src[7];
    ushort*      dst[7];
    int          m[7];      // rows (256 or 27)
};
__global__ __launch_bounds__(256) void cvt_kernel(CvtArgs a) {
    int t = blockIdx.y;
    int idx = blockIdx.x * 256 + threadIdx.x;    // m*288 + r*32 + c8
    int M = a.m[t];
    if (idx >= M * 288) return;
    int m = idx / 288, rem = idx - m * 288;
    int r = rem >> 5, c8 = rem & 31;
    const float* s = a.src[t] + ((size_t)(m * 256 + c8 * 8)) * 9 + r;
    ushort vals[8];
    #pragma unroll
    for (int j = 0; j < 8; ++j) vals[j] = f2bf(s[j * 9]);
    *(uint4*)&a.dst[t][(size_t)m * 2304 + r * 256 + c8 * 8] = *(uint4*)vals;
}

// ---------- fused prefill: bias into split-K levels (1..3) + zero offbuf ----------
struct FillArgs {
    float* outp[3];
    const float* bias[3];
    int HW[3];
    float* zbase;
    int z4;      // float4 count to zero
};
__global__ __launch_bounds__(256) void fill_kernel(FillArgs a) {
    int y = blockIdx.y;
    int i = blockIdx.x * 256 + threadIdx.x;
    if (y < 3) {
        int HW = a.HW[y];
        int total4 = (2 * 256 * HW) >> 2;
        if (i < total4) {
            int e = i << 2;
            int m = (e / HW) & 255;
            float v = a.bias[y][m];
            *(float4*)&a.outp[y][e] = float4{v, v, v, v};
        }
    } else {
        if (i < a.z4) ((float4*)a.zbase)[i] = float4{0.f, 0.f, 0.f, 0.f};
    }
}

// ---------- xs = NHWC bf16 of (x + up2(prev)); x,prev NCHW fp32 ----------
__global__ __launch_bounds__(256) void xs_nhwc(
    const float* __restrict__ x, const float* __restrict__ prev,
    ushort* __restrict__ xs, int H, int W)
{
    __shared__ ushort tile[32][72];
    const int HW = H * W, W2 = W >> 1;
    int b = blockIdx.z, c0 = blockIdx.y * 32, hw0 = blockIdx.x * 64;
    const float* xb = x + ((size_t)b * 256 + c0) * HW;
    const float* pb = prev ? prev + ((size_t)b * 256 + c0) * (HW >> 2) : nullptr;

    int hwl = threadIdx.x & 63, cl0 = threadIdx.x >> 6;
    int hw = hw0 + hwl;
    bool ok = hw < HW;
    int hwc = ok ? hw : HW - 1;
    int h = hwc / W, w = hwc - h * W;
    int pidx = (h >> 1) * W2 + (w >> 1);
    #pragma unroll
    for (int p = 0; p < 8; ++p) {
        int cl = p * 4 + cl0;
        float v = 0.f;
        if (ok) {
            v = xb[(size_t)cl * HW + hw];
            if (pb) v += pb[(size_t)cl * (HW >> 2) + pidx];
        }
        tile[cl][hwl] = f2bf(v);
    }
    __syncthreads();
    int hwl2 = threadIdx.x >> 2, cc = (threadIdx.x & 3) * 8;
    int hw2 = hw0 + hwl2;
    if (hw2 < HW) {
        ushort vals[8];
        #pragma unroll
        for (int j = 0; j < 8; ++j) vals[j] = tile[cc + j][hwl2];
        *(uint4*)&xs[((size_t)b * HW + hw2) * 256 + c0 + cc] = *(uint4*)vals;
    }
}

// ---------- offset conv: bf16 MFMA, M=27 (pad 32), split-K, dbuf ----------
__global__ __launch_bounds__(256) void off_mfma(
    const ushort* __restrict__ A, const ushort* __restrict__ xs,
    const ushort* __restrict__ zeros, float* __restrict__ offbuf,
    int N, int H, int W, int ktiles)
{
    __shared__ __align__(16) ushort As[2][32 * 32];
    __shared__ __align__(16) ushort Bs[2][64 * 32];
    const int b  = blockIdx.z;
    const int n0 = blockIdx.x * 64;
    const int kt0 = blockIdx.y * ktiles * 32;
    const int tid = threadIdx.x, lane = tid & 63, wv = tid >> 6;
    const ushort* xb = xs + (size_t)b * N * 256;

    int n = n0 + (tid >> 2); if (n >= N) n = N - 1;
    int h = n / W, w = n - h * W;
    int kcc = (tid & 3) * 8;

    auto stage = [&](int kt, int bi) {
        int r = kt >> 8, c0k = kt & 255;
        int ry = r / 3 - 1, rx = r - (r / 3) * 3 - 1;
        if (tid < 128) {
            int row = tid >> 2; if (row > 26) row = 26;
            gload_lds16(A + (size_t)row * 2304 + kt + kcc,
                        (char*)As[bi] + (size_t)(tid & ~63) * 16);
        }
        int ih = h + ry, iw = w + rx;
        const ushort* src = (ih >= 0 && ih < H && iw >= 0 && iw < W)
            ? xb + (((size_t)(ih * W + iw)) << 8) + c0k + kcc
            : zeros;
        gload_lds16(src, (char*)Bs[bi] + (size_t)(tid & ~63) * 16);
    };

    f4 acc[2] = {};
    stage(kt0, 0);
    for (int kk = 0; kk < ktiles; ++kk) {
        __syncthreads();
        if (kk + 1 < ktiles) stage(kt0 + (kk + 1) * 32, (kk + 1) & 1);
        const ushort* as = As[kk & 1];
        const ushort* bs = Bs[kk & 1];
        bfrag bf = *(const bfrag*)&bs[(wv * 16 + (lane & 15)) * 32 + (lane >> 4) * 8];
        bfrag a0 = *(const bfrag*)&as[(lane & 15) * 32 + (lane >> 4) * 8];
        bfrag a1 = *(const bfrag*)&as[(16 + (lane & 15)) * 32 + (lane >> 4) * 8];
        acc[0] = __builtin_amdgcn_mfma_f32_16x16x32_bf16(a0, bf, acc[0], 0, 0, 0);
        acc[1] = __builtin_amdgcn_mfma_f32_16x16x32_bf16(a1, bf, acc[1], 0, 0, 0);
    }

    int nn = n0 + wv * 16 + (lane & 15);
    if (nn < N) {
        #pragma unroll
        for (int mb = 0; mb < 2; ++mb)
            #pragma unroll
            for (int t = 0; t < 4; ++t) {
                int m = mb * 16 + (lane >> 4) * 4 + t;
                if (m < 27)
                    atomicAdd(&offbuf[((size_t)b * 27 + m) * N + nn], acc[mb][t]);
            }
    }
}

// ---------- deformable sampling (NHWC) -> cols[b][hw][r*256+c] bf16 ----------
__global__ __launch_bounds__(256) void sampling_kernel(
    const ushort* __restrict__ xs, const float* __restrict__ off,
    const float* __restrict__ ob, ushort* __restrict__ cols,
    int H, int W)
{
    __shared__ float4 gw[32][9];
    __shared__ int4   go[32][9];
    const int HW = H * W;
    const int b = blockIdx.z;
    const int hw0 = blockIdx.x * 32;
    const int tid = threadIdx.x;
    const float* offb = off + (size_t)b * 27 * HW;
    const ushort* xb = xs + (size_t)b * HW * 256;

    for (int it = tid; it < 32 * 9; it += 256) {
        int hwl = it / 9, k = it - hwl * 9;
        int hw = hw0 + hwl; if (hw >= HW) hw = HW - 1;
        int h = hw / W, w = hw - h * W;
        float dy = offb[(size_t)(2 * k) * HW + hw] + ob[2 * k];
        float dx = offb[(size_t)(2 * k + 1) * HW + hw] + ob[2 * k + 1];
        float mv = offb[(size_t)(18 + k) * HW + hw] + ob[18 + k];
        float mk = 1.0f / (1.0f + __expf(-mv));
        float py = (float)h - 1.0f + (float)(k / 3) + dy;
        float px = (float)w - 1.0f + (float)(k % 3) + dx;
        float y0f = floorf(py), x0f = floorf(px);
        float wy = py - y0f, wx = px - x0f;
        int y0 = (int)y0f, x0i = (int)x0f;
        int y1 = y0 + 1, x1 = x0i + 1;
        bool vy0 = (y0 >= 0) & (y0 < H), vy1 = (y1 >= 0) & (y1 < H);
        bool vx0 = (x0i >= 0) & (x0i < W), vx1 = (x1 >= 0) & (x1 < W);
        float w00 = (1.f - wy) * (1.f - wx) * ((vy0 & vx0) ? mk : 0.f);
        float w01 = (1.f - wy) * wx        * ((vy0 & vx1) ? mk : 0.f);
        float w10 = wy * (1.f - wx)        * ((vy1 & vx0) ? mk : 0.f);
        float w11 = wy * wx                * ((vy1 & vx1) ? mk : 0.f);
        int cy0 = min(max(y0, 0), H - 1), cy1 = min(max(y1, 0), H - 1);
        int cx0 = min(max(x0i, 0), W - 1), cx1 = min(max(x1, 0), W - 1);
        gw[hwl][k] = float4{w00, w01, w10, w11};
        go[hwl][k] = int4{(cy0 * W + cx0) << 8, (cy0 * W + cx1) << 8,
                          (cy1 * W + cx0) << 8, (cy1 * W + cx1) << 8};
    }
    __syncthreads();

    int hwl = tid >> 3, cb = (tid & 7) * 32;
    int hw = hw0 + hwl;
    if (hw >= HW) return;
    ushort* colp = cols + ((size_t)b * HW + hw) * 2304 + cb;

    #pragma unroll
    for (int k = 0; k < 9; ++k) {
        float4 wv = gw[hwl][k];
        int4   ov = go[hwl][k];
        const ushort* p00 = xb + ov.x + cb;
        const ushort* p01 = xb + ov.y + cb;
        const ushort* p10 = xb + ov.z + cb;
        const ushort* p11 = xb + ov.w + cb;
        #pragma unroll
        for (int j = 0; j < 4; ++j) {
            float f00[8], f01[8], f10[8], f11[8];
            bf8_to_f(*(const uint4*)(p00 + 8 * j), f00);
            bf8_to_f(*(const uint4*)(p01 + 8 * j), f01);
            bf8_to_f(*(const uint4*)(p10 + 8 * j), f10);
            bf8_to_f(*(const uint4*)(p11 + 8 * j), f11);
            unsigned int pk[4];
            #pragma unroll
            for (int t = 0; t < 4; ++t) {
                float lo = f00[2 * t] * wv.x + f01[2 * t] * wv.y +
                           f10[2 * t] * wv.z + f11[2 * t] * wv.w;
                float hi = f00[2 * t + 1] * wv.x + f01[2 * t + 1] * wv.y +
                           f10[2 * t + 1] * wv.z + f11[2 * t + 1] * wv.w;
                pk[t] = (unsigned int)f2bf(lo) | ((unsigned int)f2bf(hi) << 16);
            }
            *(uint4*)(colp + k * 256 + 8 * j) = make_uint4(pk[0], pk[1], pk[2], pk[3]);
        }
    }
}

// ---------- bf16 MFMA GEMM: tile 128m x 64n, BK=64, XOR-swizzled LDS ----------
// LDS chunk (row, c) holds global K-chunk (c ^ (row&7)); kills ds_read_b128
// bank conflicts while keeping global_load_lds lane-contiguous dst.
// grid: (ceil(N/64), 2*S, B); kchunk = 2304/S (multiple of 64).
template<bool IMPLICIT, bool SPLITK>
__global__ __launch_bounds__(256) void mfma_gemm(
    const ushort* __restrict__ A, const float* __restrict__ bias,
    const ushort* __restrict__ Bt, const ushort* __restrict__ zeros,
    float* __restrict__ outp, int N, int H, int W, int kchunk)
{
    __shared__ __align__(16) ushort As[128 * 64];
    __shared__ __align__(16) ushort Bs[64 * 64];
    const int b  = blockIdx.z;
    const int m0 = (blockIdx.y & 1) * 128;
    const int kt0 = (blockIdx.y >> 1) * kchunk;
    const int n0 = blockIdx.x * 64;
    const int tid  = threadIdx.x;
    const int lane = tid & 63;
    const int wv   = tid >> 6;
    const int wm = wv & 1, wn = wv >> 1;     // wave tile: 64m x 32n

    const ushort* Bb = IMPLICIT ? Bt + (size_t)b * N * 256
                                : Bt + (size_t)b * (size_t)N * 2304;

    // staging constants: chunk swizzle is constant per thread
    const int sc8 = ((tid & 7) ^ ((tid >> 3) & 7)) * 8;   // element offset of swizzled src chunk
    int bn[2], bh[2], bw[2];
    #pragma unroll
    for (int j = 0; j < 2; ++j) {
        int n = n0 + j * 32 + (tid >> 3); if (n >= N) n = N - 1;
        bn[j] = n; bh[j] = n / W; bw[j] = n - bh[j] * W;
    }

    auto stage = [&](int kt) {
        #pragma unroll
        for (int i = 0; i < 4; ++i) {
            int row = i * 32 + (tid >> 3);
            gload_lds16(A + (size_t)(m0 + row) * 2304 + kt + sc8,
                        (char*)As + (size_t)(i * 256 + (tid & ~63)) * 16);
        }
        if (!IMPLICIT) {
            #pragma unroll
            for (int j = 0; j < 2; ++j)
                gload_lds16(Bb + (size_t)bn[j] * 2304 + kt + sc8,
                            (char*)Bs + (size_t)(j * 256 + (tid & ~63)) * 16);
        } else {
            int r = kt >> 8, c0k = kt & 255;
            int ry = r / 3 - 1, rx = r - (r / 3) * 3 - 1;
            #pragma unroll
            for (int j = 0; j < 2; ++j) {
                int ih = bh[j] + ry, iw = bw[j] + rx;
                const ushort* src = (ih >= 0 && ih < H && iw >= 0 && iw < W)
                    ? Bb + (((size_t)(ih * W + iw)) << 8) + c0k + sc8
                    : zeros;
                gload_lds16(src, (char*)Bs + (size_t)(j * 256 + (tid & ~63)) * 16);
            }
        }
    };

    // fragment-read swizzled chunk offsets (element units), constant per lane
    const int fq = (lane >> 4);            // 0..3
    const int fv = (lane & 7);             // row&7 for this lane's rows
    f4 acc[4][2] = {};

    const int kend = kt0 + kchunk;
    for (int kt = kt0; kt < kend; kt += 64) {
        stage(kt);
        __syncthreads();
        bfrag af[2][4], bf[2][2];
        #pragma unroll
        for (int kh = 0; kh < 2; ++kh) {
            int ch = ((kh * 4 + fq) ^ fv) * 8;
            #pragma unroll
            for (int i = 0; i < 4; ++i) {
                int r = wm * 64 + i * 16 + (lane & 15);
                af[kh][i] = *(const bfrag*)&As[r * 64 + ch];
            }
            #pragma unroll
            for (int j = 0; j < 2; ++j) {
                int r = wn * 32 + j * 16 + (lane & 15);
                bf[kh][j] = *(const bfrag*)&Bs[r * 64 + ch];
            }
        }
        #pragma unroll
        for (int kh = 0; kh < 2; ++kh)
            #pragma unroll
            for (int i = 0; i < 4; ++i)
                #pragma unroll
                for (int j = 0; j < 2; ++j)
                    acc[i][j] = __builtin_amdgcn_mfma_f32_16x16x32_bf16(
                        af[kh][i], bf[kh][j], acc[i][j], 0, 0, 0);
        __syncthreads();
    }

    const int mb = m0 + wm * 64, nb = n0 + wn * 32;
    #pragma unroll
    for (int i = 0; i < 4; ++i) {
        int mrow = mb + i * 16 + (lane >> 4) * 4;
        #pragma unroll
        for (int j = 0; j < 2; ++j) {
            int n = nb + j * 16 + (lane & 15);
            if (n < N) {
                #pragma unroll
                for (int t = 0; t < 4; ++t) {
                    int m = mrow + t;
                    if (SPLITK)
                        atomicAdd(&outp[((size_t)b * 256 + m) * N + n], acc[i][j][t]);
                    else
                        outp[((size_t)b * 256 + m) * N + n] = acc[i][j][t] + bias[m];
                }
            }
        }
    }
}

// ---------- host launch ----------
extern "C" void kernel_launch(void* const* d_in, const int* in_sizes, int n_in,
                              void* d_out, int out_size, void* d_ws, size_t ws_size,
                              hipStream_t stream)
{
    const float* x[4]   = {(const float*)d_in[0], (const float*)d_in[1],
                           (const float*)d_in[2], (const float*)d_in[3]};
    const float* wgt[4] = {(const float*)d_in[4], (const float*)d_in[6],
                           (const float*)d_in[8], (const float*)d_in[10]};
    const float* bia[4] = {(const float*)d_in[5], (const float*)d_in[7],
                           (const float*)d_in[9], (const float*)d_in[11]};
    const float* owt[4] = {nullptr, (const float*)d_in[12],
                           (const float*)d_in[14], (const float*)d_in[16]};
    const float* obv[4] = {nullptr, (const float*)d_in[13],
                           (const float*)d_in[15], (const float*)d_in[17]};

    const int B = 2;
    const int Hs[4] = {96, 48, 24, 12};
    const int HWs[4] = {96 * 96, 48 * 48, 24 * 24, 12 * 12};

    float* out = (float*)d_out;
    size_t outOff[4];
    outOff[0] = 0;
    outOff[1] = outOff[0] + (size_t)B * 256 * HWs[0];
    outOff[2] = outOff[1] + (size_t)B * 256 * HWs[1];
    outOff[3] = outOff[2] + (size_t)B * 256 * HWs[2];

    // ---- ws carve (256B aligned)
    char* ws = (char*)d_ws;
    size_t off = 0;
    auto carve = [&](size_t bytes) { void* p = ws + off; off = (off + bytes + 255) & ~(size_t)255; return p; };
    ushort* wbf[4];
    ushort* owbf[4] = {nullptr, nullptr, nullptr, nullptr};
    for (int i = 0; i < 4; ++i) wbf[i] = (ushort*)carve((size_t)256 * 2304 * 2);
    for (int i = 1; i < 4; ++i) owbf[i] = (ushort*)carve((size_t)27 * 2304 * 2);
    ushort* cols = (ushort*)carve((size_t)B * HWs[1] * 2304 * 2);   // max: level 1
    ushort* xsb[4];
    for (int i = 0; i < 4; ++i) xsb[i] = (ushort*)carve((size_t)B * 256 * HWs[i] * 2);
    int offElems = B * 27 * (HWs[1] + HWs[2] + HWs[3]);
    float* offbase = (float*)carve((size_t)offElems * 4 + 1024);
    ushort* zeros = (ushort*)(offbase + offElems);   // 1 KB zero page
    float* offbuf[4] = {nullptr,
                        offbase,
                        offbase + (size_t)B * 27 * HWs[1],
                        offbase + (size_t)B * 27 * (HWs[1] + HWs[2])};

    // ---- upfront: weight cvt+reorder
    {
        CvtArgs a;
        a.src[0] = wgt[0]; a.src[1] = wgt[1]; a.src[2] = wgt[2]; a.src[3] = wgt[3];
        a.src[4] = owt[1]; a.src[5] = owt[2]; a.src[6] = owt[3];
        a.dst[0] = wbf[0]; a.dst[1] = wbf[1]; a.dst[2] = wbf[2]; a.dst[3] = wbf[3];
        a.dst[4] = owbf[1]; a.dst[5] = owbf[2]; a.dst[6] = owbf[3];
        for (int i = 0; i < 4; ++i) a.m[i] = 256;
        for (int i = 4; i < 7; ++i) a.m[i] = 27;
        dim3 grd((256 * 288 + 255) / 256, 7);
        cvt_kernel<<<grd, 256, 0, stream>>>(a);
    }
    // ---- upfront: bias prefill for split-K levels (1..3) + offbuf/zeropage zero
    {
        FillArgs a;
        for (int i = 0; i < 3; ++i) {
            a.outp[i] = out + outOff[i + 1]; a.bias[i] = bia[i + 1]; a.HW[i] = HWs[i + 1];
        }
        a.zbase = offbase;
        a.z4 = (offElems * 4 + 1024) / 16;
        int maxE = 2 * 256 * HWs[1] / 4;
        if (a.z4 > maxE) maxE = a.z4;
        dim3 grd((maxE + 255) / 256, 4);
        fill_kernel<<<grd, 256, 0, stream>>>(a);
    }
    {
        dim3 grd((HWs[3] + 63) / 64, 8, B);
        xs_nhwc<<<grd, 256, 0, stream>>>(x[3], nullptr, xsb[3], Hs[3], Hs[3]);
    }

    const int ktiles[4] = {0, 9, 6, 3};    // off-conv split-K chunking (BK=32)
    const int ksplit[4] = {1, 2, 6, 12};   // main-gemm split-K; 2304/S % 64 == 0

    for (int lvl = 3; lvl >= 1; --lvl) {
        int H = Hs[lvl], W = H, HW = HWs[lvl];

        // offset conv (bf16 MFMA split-K, NHWC implicit staging, dbuf)
        {
            dim3 grd((HW + 63) / 64, 72 / ktiles[lvl], B);
            off_mfma<<<grd, 256, 0, stream>>>(
                owbf[lvl], xsb[lvl], zeros, offbuf[lvl], HW, H, W, ktiles[lvl]);
        }
        // deformable sampling -> cols [b][hw][r*256+c]
        {
            dim3 grd((HW + 31) / 32, 1, B);
            sampling_kernel<<<grd, 256, 0, stream>>>(
                xsb[lvl], offbuf[lvl], obv[lvl], cols, H, W);
        }
        // main conv: split-K MFMA GEMM into bias-prefilled out
        {
            dim3 grd((HW + 63) / 64, 2 * ksplit[lvl], B);
            mfma_gemm<false, true><<<grd, 256, 0, stream>>>(
                wbf[lvl], bia[lvl], cols, zeros, out + outOff[lvl],
                HW, H, W, 2304 / ksplit[lvl]);
        }
        // xs for next-finer level
        {
            int Hn = Hs[lvl - 1];
            dim3 grd((HWs[lvl - 1] + 63) / 64, 8, B);
            xs_nhwc<<<grd, 256, 0, stream>>>(
                x[lvl - 1], out + outOff[lvl], xsb[lvl - 1], Hn, Hn);
        }
    }

    // level 0: implicit NHWC MFMA GEMM, direct bias write (no split-K)
    {
        dim3 grd((HWs[0] + 63) / 64, 2, B);
        mfma_gemm<true, false><<<grd, 256, 0, stream>>>(
            wbf[0], bia[0], xsb[0], zeros, out + outOff[0],
            HWs[0], Hs[0], Hs[0], 2304);
    }
}